// Round 7
// baseline (289.216 us; speedup 1.0000x reference)
//
#include <hip/hip_runtime.h>

// MHA: B=2, S=2048, D=1024, H=16, HD=64. fp32 in/out, bf16 MFMA internally.
// ws layout (64 MB): qb/kb/vb bf16 @0/8/16MB (qb/kb dead after proj3;
// O-accum fp32 [32bh][2048][64] reuses 0-16MB); Wq/k/v/o^T bf16 @24/26/28/30MB;
// q(pre-scaled 0.125*log2e),k [B,H,S,HD] @32/40MB; v^T [B,H,HD,S] @48MB;
// bm u64[2048][32] @56MB; l-accum fp32 [32][2048] @56.75MB; ctx bf16 @16MB.
//
// flash split-K=2: grid 1024 blocks (4/CU, 4 waves/SIMD); each block does
// 1024 keys, atomicAdd's unnormalized fp32 O and l; combine_kernel divides.
// GEMMs: 64x128 tiles, global_load_lds(16B), n-major grid for A L2 reuse.

using s8v = __attribute__((ext_vector_type(8))) short;   // 8 bf16 (4 VGPRs)
using f4v = __attribute__((ext_vector_type(4))) float;   // MFMA acc
typedef unsigned long long u64;

__device__ __forceinline__ unsigned short f2bf(float f) {
  union { float f; unsigned int u; } v; v.f = f;
  return (unsigned short)((v.u + 0x7fffu + ((v.u >> 16) & 1u)) >> 16);  // RNE
}

__device__ __forceinline__ void gll16(const void* g, void* l) {
  __builtin_amdgcn_global_load_lds(
      (const __attribute__((address_space(1))) unsigned int*)g,
      (__attribute__((address_space(3))) unsigned int*)l, 16, 0, 0);
}

// ---------- merged prep: f2b (QKV), wtrans (4 weights), packmask ----------
__global__ void prep_kernel(const float* __restrict__ Q, const float* __restrict__ K,
                            const float* __restrict__ V,
                            unsigned short* __restrict__ qb, unsigned short* __restrict__ kb,
                            unsigned short* __restrict__ vb,
                            const float* __restrict__ W0, const float* __restrict__ W1,
                            const float* __restrict__ W2, const float* __restrict__ W3,
                            unsigned short* __restrict__ T0, unsigned short* __restrict__ T1,
                            unsigned short* __restrict__ T2, unsigned short* __restrict__ T3,
                            const int* __restrict__ mask, u64* __restrict__ bm) {
  __shared__ unsigned short t[64][72];
  const int bid = blockIdx.x, tid = threadIdx.x;
  if (bid < 12288) {
    int z = bid >> 12;
    int idx = (bid & 4095) * 256 + tid;
    const float* in = (z == 0) ? Q : (z == 1) ? K : V;
    unsigned short* out = (z == 0) ? qb : (z == 1) ? kb : vb;
    float4 v = ((const float4*)in)[idx];
    ushort4 o;
    o.x = f2bf(v.x); o.y = f2bf(v.y); o.z = f2bf(v.z); o.w = f2bf(v.w);
    ((ushort4*)out)[idx] = o;
  } else if (bid < 13312) {
    int b = bid - 12288;
    int z = b >> 8, rem = b & 255;
    int k0 = (rem >> 4) * 64, n0 = (rem & 15) * 64;
    const float* W = (z == 0) ? W0 : (z == 1) ? W1 : (z == 2) ? W2 : W3;
    unsigned short* Wt = (z == 0) ? T0 : (z == 1) ? T1 : (z == 2) ? T2 : T3;
    for (int p = 0; p < 4; ++p) {
      int idx = p * 256 + tid;
      int row = idx >> 4, c4 = idx & 15;
      float4 v = *(const float4*)&W[(size_t)(k0 + row) * 1024 + n0 + c4 * 4];
      t[row][c4 * 4 + 0] = f2bf(v.x);
      t[row][c4 * 4 + 1] = f2bf(v.y);
      t[row][c4 * 4 + 2] = f2bf(v.z);
      t[row][c4 * 4 + 3] = f2bf(v.w);
    }
    __syncthreads();
    for (int p = 0; p < 2; ++p) {
      int idx = p * 256 + tid;
      int j = idx >> 3, c8 = idx & 7;
      unsigned short tmp[8];
      for (int i = 0; i < 8; ++i) tmp[i] = t[c8 * 8 + i][j];
      uint4 o;
      o.x = tmp[0] | ((unsigned)tmp[1] << 16);
      o.y = tmp[2] | ((unsigned)tmp[3] << 16);
      o.z = tmp[4] | ((unsigned)tmp[5] << 16);
      o.w = tmp[6] | ((unsigned)tmp[7] << 16);
      *(uint4*)&Wt[(size_t)(n0 + j) * 1024 + k0 + c8 * 8] = o;
    }
  } else {
    int b = bid - 13312;
    int gw = (b * 256 + tid) >> 6;
    int lane = tid & 63;
    int mv = mask[(size_t)gw * 64 + lane];
    u64 bal = __ballot(mv != 0);
    if (lane == 0) bm[gw] = bal;
  }
}

// ---------- fused QKV projection GEMM, 64x128 tile, n-major grid ----------
// z=0: q*(0.125*log2e) -> [B,H,S,HD]; z=1: k -> [B,H,S,HD]; z=2: v -> v^T [B,H,HD,S]
__global__ __launch_bounds__(256) void proj3_kernel(
    const unsigned short* __restrict__ A0, const unsigned short* __restrict__ A1,
    const unsigned short* __restrict__ A2,
    const unsigned short* __restrict__ W0, const unsigned short* __restrict__ W1,
    const unsigned short* __restrict__ W2,
    const float* __restrict__ b0, const float* __restrict__ b1, const float* __restrict__ b2,
    unsigned short* __restrict__ oq, unsigned short* __restrict__ ok,
    unsigned short* __restrict__ ovt) {
  const int z = blockIdx.z;
  const unsigned short* A  = (z == 0) ? A0 : (z == 1) ? A1 : A2;
  const unsigned short* Wt = (z == 0) ? W0 : (z == 1) ? W1 : W2;
  const float* bias        = (z == 0) ? b0 : (z == 1) ? b1 : b2;

  __shared__ __align__(16) unsigned short As[64 * 32];
  __shared__ __align__(16) unsigned short Bs[128 * 32];

  const int tid = threadIdx.x;
  const int lane = tid & 63, w = tid >> 6, ln = lane & 15, quad = lane >> 4;
  const int wm = (w & 1) * 32, wn = (w >> 1) * 64;
  const int n0 = blockIdx.x * 128, m0 = blockIdx.y * 64;

  const int slr = lane >> 2;
  const int schunk = (lane & 3) ^ ((lane >> 3) & 3);
  const int cfrag = (quad ^ ((ln >> 1) & 3)) * 8;

  f4v zero = {0.f, 0.f, 0.f, 0.f};
  f4v acc[2][4];
  for (int mi = 0; mi < 2; ++mi)
    for (int ni = 0; ni < 4; ++ni) acc[mi][ni] = zero;

  for (int kt = 0; kt < 1024; kt += 32) {
    __syncthreads();
    gll16(&A[(size_t)(m0 + w * 16 + slr) * 1024 + kt + schunk * 8],        &As[(w * 16) * 32]);
    gll16(&Wt[(size_t)(n0 + w * 32 + slr) * 1024 + kt + schunk * 8],       &Bs[(w * 32) * 32]);
    gll16(&Wt[(size_t)(n0 + w * 32 + 16 + slr) * 1024 + kt + schunk * 8],  &Bs[(w * 32 + 16) * 32]);
    __syncthreads();
    s8v a[2], b[4];
    for (int mi = 0; mi < 2; ++mi) a[mi] = *(const s8v*)&As[(wm + mi * 16 + ln) * 32 + cfrag];
    for (int ni = 0; ni < 4; ++ni) b[ni] = *(const s8v*)&Bs[(wn + ni * 16 + ln) * 32 + cfrag];
    if (z < 2) {
      for (int mi = 0; mi < 2; ++mi)
        for (int ni = 0; ni < 4; ++ni)
          acc[mi][ni] = __builtin_amdgcn_mfma_f32_16x16x32_bf16(a[mi], b[ni], acc[mi][ni], 0, 0, 0);
    } else {
      for (int mi = 0; mi < 2; ++mi)
        for (int ni = 0; ni < 4; ++ni)
          acc[mi][ni] = __builtin_amdgcn_mfma_f32_16x16x32_bf16(b[ni], a[mi], acc[mi][ni], 0, 0, 0);
    }
  }

  if (z < 2) {
    const float qscale = (z == 0) ? 0.18033688f : 1.0f;  // 0.125 * log2(e)
    unsigned short* outp = (z == 0) ? oq : ok;
    for (int mi = 0; mi < 2; ++mi) {
      int rb = m0 + wm + mi * 16 + quad * 4;
      int b_ = rb >> 11;
      for (int ni = 0; ni < 4; ++ni) {
        int col = n0 + wn + ni * 16 + ln;
        float bvv = bias[col];
        int h = col >> 6, hd = col & 63;
        size_t ob = (size_t)(b_ * 16 + h) * 2048;
        for (int r = 0; r < 4; ++r) {
          int s = (rb + r) & 2047;
          outp[(ob + s) * 64 + hd] = f2bf((acc[mi][ni][r] + bvv) * qscale);
        }
      }
    }
  } else {
    for (int ni = 0; ni < 4; ++ni) {
      for (int r = 0; r < 4; ++r) {
        int colw = n0 + wn + ni * 16 + quad * 4 + r;
        int h = colw >> 6, hd = colw & 63;
        float bvv = bias[colw];
        for (int mi = 0; mi < 2; ++mi) {
          int sg = m0 + wm + mi * 16 + ln;
          int b_ = sg >> 11, ss = sg & 2047;
          ovt[((size_t)(b_ * 16 + h) * 64 + hd) * 2048 + ss] = f2bf(acc[mi][ni][r] + bvv);
        }
      }
    }
  }
}

// ---------- flash attention split-K=2: atomicAdd fp32 partials ----------
// q[B,H,S,HD] (pre-scaled), k[B,H,S,HD], v^T[B,H,HD,S]
// o_glob fp32 [32bh][2048][64], l_glob fp32 [32bh][2048] (both pre-zeroed)
__global__ __launch_bounds__(256) void flash_kernel(
    const unsigned short* __restrict__ q, const unsigned short* __restrict__ k,
    const unsigned short* __restrict__ vt, const u64* __restrict__ bm,
    float* __restrict__ o_glob, float* __restrict__ l_glob) {
  __shared__ __align__(16) unsigned short qp_s[128][72];  // q tile, then P[qrow][key]
  __shared__ __align__(16) unsigned short k_s[64][72];
  __shared__ __align__(16) unsigned short v_s[80][72];    // rows 64..79: ones row + zeros

  const int tid = threadIdx.x;
  const int lane = tid & 63, w = tid >> 6, ln = lane & 15, quad = lane >> 4;
  const int qt = blockIdx.x & 15, kc = blockIdx.x >> 4;
  const int q0 = qt * 128;
  const int bh = blockIdx.y;
  const unsigned short* qg  = q  + ((size_t)bh * 2048 + q0) * 64;
  const unsigned short* kgb = k  + ((size_t)bh * 2048 + kc * 1024) * 64;
  const unsigned short* vgb = vt + (size_t)bh * 64 * 2048 + kc * 1024;

  for (int j = 0; j < 5; ++j) {
    int idx = j * 256 + tid;
    if (idx < 16 * 72) ((unsigned short*)v_s[64])[idx] = 0;
  }
  for (int p = 0; p < 4; ++p) {
    int c = p * 256 + tid;
    int row = c >> 3, c8 = c & 7;
    *(uint4*)&qp_s[row][c8 * 8] = *(const uint4*)&qg[(size_t)row * 64 + c8 * 8];
  }
  __syncthreads();
  if (tid < 64) v_s[64][tid] = 0x3F80;  // 1.0bf16
  __syncthreads();

  s8v aq[2][2];
  for (int s = 0; s < 2; ++s)
    for (int h = 0; h < 2; ++h)
      aq[s][h] = *(const s8v*)&qp_s[s * 64 + w * 16 + ln][h * 32 + quad * 8];
  s8v bones0 = *(const s8v*)&v_s[64 + ln][quad * 8];
  s8v bones1 = *(const s8v*)&v_s[64 + ln][32 + quad * 8];

  const int srow0 = tid >> 3, sc8 = tid & 7;
  const int srow1 = 32 + srow0;

  const u64* bmr0 = bm + (size_t)(q0 + w * 16 + ln) * 32 + kc * 16;
  const u64* bmr1 = bmr0 + 64 * 32;

  uint4 kr0 = *(const uint4*)&kgb[(size_t)srow0 * 64 + sc8 * 8];
  uint4 kr1 = *(const uint4*)&kgb[(size_t)srow1 * 64 + sc8 * 8];
  uint4 vr0 = *(const uint4*)&vgb[(size_t)srow0 * 2048 + sc8 * 8];
  uint4 vr1 = *(const uint4*)&vgb[(size_t)srow1 * 2048 + sc8 * 8];
  u64 mwc[2], mwn[2];
  mwc[0] = bmr0[0];
  mwc[1] = bmr1[0];

  f4v zero = {0.f, 0.f, 0.f, 0.f};
  f4v l_acc[2];
  f4v o_acc[2][4];
  for (int s = 0; s < 2; ++s) {
    l_acc[s] = zero;
    for (int ni = 0; ni < 4; ++ni) o_acc[s][ni] = zero;
  }

  for (int kt = 0; kt < 1024; kt += 64) {
    *(uint4*)&k_s[srow0][sc8 * 8] = kr0;
    *(uint4*)&k_s[srow1][sc8 * 8] = kr1;
    *(uint4*)&v_s[srow0][sc8 * 8] = vr0;
    *(uint4*)&v_s[srow1][sc8 * 8] = vr1;
    if (kt + 64 < 1024) {
      int ktn = kt + 64;
      kr0 = *(const uint4*)&kgb[(size_t)(ktn + srow0) * 64 + sc8 * 8];
      kr1 = *(const uint4*)&kgb[(size_t)(ktn + srow1) * 64 + sc8 * 8];
      vr0 = *(const uint4*)&vgb[(size_t)srow0 * 2048 + ktn + sc8 * 8];
      vr1 = *(const uint4*)&vgb[(size_t)srow1 * 2048 + ktn + sc8 * 8];
      int ktcn = ktn >> 6;
      mwn[0] = bmr0[ktcn];
      mwn[1] = bmr1[ktcn];
    }
    __syncthreads();

    f4v sc[2][4];
    for (int ni = 0; ni < 4; ++ni) {
      s8v ak0 = *(const s8v*)&k_s[ni * 16 + ln][quad * 8];
      s8v ak1 = *(const s8v*)&k_s[ni * 16 + ln][32 + quad * 8];
      for (int s = 0; s < 2; ++s) {
        f4v t = zero;
        t = __builtin_amdgcn_mfma_f32_16x16x32_bf16(ak0, aq[s][0], t, 0, 0, 0);
        t = __builtin_amdgcn_mfma_f32_16x16x32_bf16(ak1, aq[s][1], t, 0, 0, 0);
        sc[s][ni] = t;
      }
    }

    for (int s = 0; s < 2; ++s) {
      u64 m = mwc[s] >> (quad * 4);
      unsigned mlo = (unsigned)m, mhi = (unsigned)(m >> 32);
      for (int ni = 0; ni < 4; ++ni) {
        unsigned msel = ((ni < 2) ? mlo : mhi) >> ((ni & 1) * 16);
        unsigned u0 = __float_as_uint(__builtin_amdgcn_exp2f(sc[s][ni][0]) * (float)(msel & 1u));
        unsigned u1 = __float_as_uint(__builtin_amdgcn_exp2f(sc[s][ni][1]) * (float)((msel >> 1) & 1u));
        unsigned u2 = __float_as_uint(__builtin_amdgcn_exp2f(sc[s][ni][2]) * (float)((msel >> 2) & 1u));
        unsigned u3 = __float_as_uint(__builtin_amdgcn_exp2f(sc[s][ni][3]) * (float)((msel >> 3) & 1u));
        unsigned plo = __builtin_amdgcn_perm(u1, u0, 0x07060302);
        unsigned phi = __builtin_amdgcn_perm(u3, u2, 0x07060302);
        *(u64*)&qp_s[s * 64 + w * 16 + ln][ni * 16 + quad * 4] = plo | ((u64)phi << 32);
      }
      mwc[s] = mwn[s];
    }

    s8v ap[2][2];
    for (int s = 0; s < 2; ++s)
      for (int h = 0; h < 2; ++h)
        ap[s][h] = *(const s8v*)&qp_s[s * 64 + w * 16 + ln][h * 32 + quad * 8];
    for (int ni = 0; ni < 4; ++ni) {
      s8v bv0 = *(const s8v*)&v_s[ni * 16 + ln][quad * 8];
      s8v bv1 = *(const s8v*)&v_s[ni * 16 + ln][32 + quad * 8];
      for (int s = 0; s < 2; ++s) {
        o_acc[s][ni] = __builtin_amdgcn_mfma_f32_16x16x32_bf16(ap[s][0], bv0, o_acc[s][ni], 0, 0, 0);
        o_acc[s][ni] = __builtin_amdgcn_mfma_f32_16x16x32_bf16(ap[s][1], bv1, o_acc[s][ni], 0, 0, 0);
      }
    }
    for (int s = 0; s < 2; ++s) {
      l_acc[s] = __builtin_amdgcn_mfma_f32_16x16x32_bf16(ap[s][0], bones0, l_acc[s], 0, 0, 0);
      l_acc[s] = __builtin_amdgcn_mfma_f32_16x16x32_bf16(ap[s][1], bones1, l_acc[s], 0, 0, 0);
    }
    __syncthreads();
  }

  // accumulate unnormalized partials (2 contributors per location)
  float* og = o_glob + (size_t)bh * 2048 * 64;
  for (int s = 0; s < 2; ++s) {
    for (int ni = 0; ni < 4; ++ni)
      for (int r = 0; r < 4; ++r) {
        int srow = q0 + s * 64 + w * 16 + quad * 4 + r;
        atomicAdd(&og[(size_t)srow * 64 + ni * 16 + ln], o_acc[s][ni][r]);
      }
    if (ln == 0) {
      for (int r = 0; r < 4; ++r) {
        int srow = q0 + s * 64 + w * 16 + quad * 4 + r;
        atomicAdd(&l_glob[bh * 2048 + srow], l_acc[s][r]);
      }
    }
  }
}

// ---------- combine: ctx = bf16(O / l), [bh][s][hd] -> [b][s][h*64+hd] ----------
__global__ void combine_kernel(const float* __restrict__ o, const float* __restrict__ l,
                               unsigned short* __restrict__ ctx) {
  int idx = blockIdx.x * 256 + threadIdx.x;   // float4 unit
  float4 v = ((const float4*)o)[idx];
  int e = idx * 4;
  int row = e >> 6;                           // bh*2048 + s
  float inv = 1.f / l[row];
  int bh = row >> 11, srow = row & 2047;
  int b_ = bh >> 4, h = bh & 15;
  int hd = e & 63;
  ushort4 pk;
  pk.x = f2bf(v.x * inv);
  pk.y = f2bf(v.y * inv);
  pk.z = f2bf(v.z * inv);
  pk.w = f2bf(v.w * inv);
  *(ushort4*)&ctx[((size_t)(b_ * 2048 + srow)) * 1024 + h * 64 + hd] = pk;
}

// ---------- output projection, 64x128 tile, n-major grid ----------
__global__ __launch_bounds__(256) void gemm_out_kernel(
    const unsigned short* __restrict__ A, const unsigned short* __restrict__ Wt,
    const float* __restrict__ bias, float* __restrict__ out) {
  __shared__ __align__(16) unsigned short As[64 * 32];
  __shared__ __align__(16) unsigned short Bs[128 * 32];

  const int tid = threadIdx.x;
  const int lane = tid & 63, w = tid >> 6, ln = lane & 15, quad = lane >> 4;
  const int wm = (w & 1) * 32, wn = (w >> 1) * 64;
  const int n0 = blockIdx.x * 128, m0 = blockIdx.y * 64;

  const int slr = lane >> 2;
  const int schunk = (lane & 3) ^ ((lane >> 3) & 3);
  const int cfrag = (quad ^ ((ln >> 1) & 3)) * 8;

  f4v zero = {0.f, 0.f, 0.f, 0.f};
  f4v acc[2][4];
  for (int mi = 0; mi < 2; ++mi)
    for (int ni = 0; ni < 4; ++ni) acc[mi][ni] = zero;

  for (int kt = 0; kt < 1024; kt += 32) {
    __syncthreads();
    gll16(&A[(size_t)(m0 + w * 16 + slr) * 1024 + kt + schunk * 8],        &As[(w * 16) * 32]);
    gll16(&Wt[(size_t)(n0 + w * 32 + slr) * 1024 + kt + schunk * 8],       &Bs[(w * 32) * 32]);
    gll16(&Wt[(size_t)(n0 + w * 32 + 16 + slr) * 1024 + kt + schunk * 8],  &Bs[(w * 32 + 16) * 32]);
    __syncthreads();
    s8v a[2], b[4];
    for (int mi = 0; mi < 2; ++mi) a[mi] = *(const s8v*)&As[(wm + mi * 16 + ln) * 32 + cfrag];
    for (int ni = 0; ni < 4; ++ni) b[ni] = *(const s8v*)&Bs[(wn + ni * 16 + ln) * 32 + cfrag];
    for (int mi = 0; mi < 2; ++mi)
      for (int ni = 0; ni < 4; ++ni)
        acc[mi][ni] = __builtin_amdgcn_mfma_f32_16x16x32_bf16(a[mi], b[ni], acc[mi][ni], 0, 0, 0);
  }

  for (int mi = 0; mi < 2; ++mi) {
    int rb = m0 + wm + mi * 16 + quad * 4;
    for (int ni = 0; ni < 4; ++ni) {
      int col = n0 + wn + ni * 16 + ln;
      float bvv = bias[col];
      for (int r = 0; r < 4; ++r)
        out[(size_t)(rb + r) * 1024 + col] = acc[mi][ni][r] + bvv;
    }
  }
}

extern "C" void kernel_launch(void* const* d_in, const int* in_sizes, int n_in,
                              void* d_out, int out_size, void* d_ws, size_t ws_size,
                              hipStream_t stream) {
  const float* Q  = (const float*)d_in[0];
  const float* K  = (const float*)d_in[1];
  const float* V  = (const float*)d_in[2];
  const int* mask = (const int*)d_in[3];
  const float* Wq = (const float*)d_in[4];
  const float* bq = (const float*)d_in[5];
  const float* Wk = (const float*)d_in[6];
  const float* bk = (const float*)d_in[7];
  const float* Wv = (const float*)d_in[8];
  const float* bv = (const float*)d_in[9];
  const float* Wo = (const float*)d_in[10];
  const float* bo = (const float*)d_in[11];
  float* out = (float*)d_out;

  char* ws = (char*)d_ws;
  const size_t MB = 1u << 20;
  unsigned short* qb  = (unsigned short*)(ws + 0 * MB);
  unsigned short* kb  = (unsigned short*)(ws + 8 * MB);
  unsigned short* vb  = (unsigned short*)(ws + 16 * MB);
  unsigned short* wqt = (unsigned short*)(ws + 24 * MB);
  unsigned short* wkt = (unsigned short*)(ws + 26 * MB);
  unsigned short* wvt = (unsigned short*)(ws + 28 * MB);
  unsigned short* wot = (unsigned short*)(ws + 30 * MB);
  unsigned short* qh  = (unsigned short*)(ws + 32 * MB);
  unsigned short* kh  = (unsigned short*)(ws + 40 * MB);
  unsigned short* vth = (unsigned short*)(ws + 48 * MB);
  u64* bm             = (u64*)(ws + 56 * MB);
  float* l_glob       = (float*)(ws + 56 * MB + 786432);   // @56.75MB, 0.25MB
  float* o_glob       = (float*)(ws + 0 * MB);             // 16MB, reuses qb+kb
  unsigned short* ctx = (unsigned short*)(ws + 16 * MB);   // reuses vb

  prep_kernel<<<29696, 256, 0, stream>>>(Q, K, V, qb, kb, vb,
                                         Wq, Wk, Wv, Wo, wqt, wkt, wvt, wot,
                                         mask, bm);
  proj3_kernel<<<dim3(8, 64, 3), 256, 0, stream>>>(qb, kb, vb, wqt, wkt, wvt,
                                                   bq, bk, bv, qh, kh, vth);
  hipMemsetAsync(o_glob, 0, 16 * MB, stream);
  hipMemsetAsync(l_glob, 0, 262144, stream);
  flash_kernel<<<dim3(32, 32), 256, 0, stream>>>(qh, kh, vth, bm, o_glob, l_glob);
  combine_kernel<<<4096, 256, 0, stream>>>(o_glob, l_glob, ctx);
  gemm_out_kernel<<<dim3(8, 64), 256, 0, stream>>>(ctx, wot, bo, out);
}

// Round 8
// 264.565 us; speedup vs baseline: 1.0932x; 1.0932x over previous
//
#include <hip/hip_runtime.h>

// MHA: B=2, S=2048, D=1024, H=16, HD=64. fp32 in/out, bf16 MFMA internally.
// ws layout (64 MB): qb/kb/vb bf16 [4096,1024] @0/8/16MB; Wq/k/v/o^T bf16
// [1024,1024] @24/26/28/30MB; q(pre-scaled 0.125*log2e),k [B,H,S,HD] @32/40MB;
// v^T [B,H,HD,S] @48MB; bm u64[2048][32] @56MB; ctx bf16 @16MB (aliases vb).
//
// R8: flash reverted to R6 (split-K regressed: atomics+extra launches cost
// more than 4-block occupancy gained). proj3 upgraded to m97-class 128x128
// tile (16 MFMA : 8 ds_read_b128 : 4 gll16 per wave-iter), grid 8x32x3 = 768
// = 3 blocks/CU. gemm_out stays 64x128 (2/CU). Swizzle (R6-verified): lane i
// loads global chunk (i&3)^((i>>3)&3); frag read chunk quad^((ln>>1)&3).

using s8v = __attribute__((ext_vector_type(8))) short;   // 8 bf16 (4 VGPRs)
using f4v = __attribute__((ext_vector_type(4))) float;   // MFMA acc
typedef unsigned long long u64;

__device__ __forceinline__ unsigned short f2bf(float f) {
  union { float f; unsigned int u; } v; v.f = f;
  return (unsigned short)((v.u + 0x7fffu + ((v.u >> 16) & 1u)) >> 16);  // RNE
}

__device__ __forceinline__ void gll16(const void* g, void* l) {
  __builtin_amdgcn_global_load_lds(
      (const __attribute__((address_space(1))) unsigned int*)g,
      (__attribute__((address_space(3))) unsigned int*)l, 16, 0, 0);
}

// ---------- merged prep: f2b (QKV), wtrans (4 weights), packmask ----------
__global__ void prep_kernel(const float* __restrict__ Q, const float* __restrict__ K,
                            const float* __restrict__ V,
                            unsigned short* __restrict__ qb, unsigned short* __restrict__ kb,
                            unsigned short* __restrict__ vb,
                            const float* __restrict__ W0, const float* __restrict__ W1,
                            const float* __restrict__ W2, const float* __restrict__ W3,
                            unsigned short* __restrict__ T0, unsigned short* __restrict__ T1,
                            unsigned short* __restrict__ T2, unsigned short* __restrict__ T3,
                            const int* __restrict__ mask, u64* __restrict__ bm) {
  __shared__ unsigned short t[64][72];
  const int bid = blockIdx.x, tid = threadIdx.x;
  if (bid < 12288) {
    int z = bid >> 12;
    int idx = (bid & 4095) * 256 + tid;
    const float* in = (z == 0) ? Q : (z == 1) ? K : V;
    unsigned short* out = (z == 0) ? qb : (z == 1) ? kb : vb;
    float4 v = ((const float4*)in)[idx];
    ushort4 o;
    o.x = f2bf(v.x); o.y = f2bf(v.y); o.z = f2bf(v.z); o.w = f2bf(v.w);
    ((ushort4*)out)[idx] = o;
  } else if (bid < 13312) {
    int b = bid - 12288;
    int z = b >> 8, rem = b & 255;
    int k0 = (rem >> 4) * 64, n0 = (rem & 15) * 64;
    const float* W = (z == 0) ? W0 : (z == 1) ? W1 : (z == 2) ? W2 : W3;
    unsigned short* Wt = (z == 0) ? T0 : (z == 1) ? T1 : (z == 2) ? T2 : T3;
    for (int p = 0; p < 4; ++p) {
      int idx = p * 256 + tid;
      int row = idx >> 4, c4 = idx & 15;
      float4 v = *(const float4*)&W[(size_t)(k0 + row) * 1024 + n0 + c4 * 4];
      t[row][c4 * 4 + 0] = f2bf(v.x);
      t[row][c4 * 4 + 1] = f2bf(v.y);
      t[row][c4 * 4 + 2] = f2bf(v.z);
      t[row][c4 * 4 + 3] = f2bf(v.w);
    }
    __syncthreads();
    for (int p = 0; p < 2; ++p) {
      int idx = p * 256 + tid;
      int j = idx >> 3, c8 = idx & 7;
      unsigned short tmp[8];
      for (int i = 0; i < 8; ++i) tmp[i] = t[c8 * 8 + i][j];
      uint4 o;
      o.x = tmp[0] | ((unsigned)tmp[1] << 16);
      o.y = tmp[2] | ((unsigned)tmp[3] << 16);
      o.z = tmp[4] | ((unsigned)tmp[5] << 16);
      o.w = tmp[6] | ((unsigned)tmp[7] << 16);
      *(uint4*)&Wt[(size_t)(n0 + j) * 1024 + k0 + c8 * 8] = o;
    }
  } else {
    int b = bid - 13312;
    int gw = (b * 256 + tid) >> 6;
    int lane = tid & 63;
    int mv = mask[(size_t)gw * 64 + lane];
    u64 bal = __ballot(mv != 0);
    if (lane == 0) bm[gw] = bal;
  }
}

// ---------- fused QKV projection GEMM, 128x128 tile (m97-class) ----------
// z=0: q*(0.125*log2e) -> [B,H,S,HD]; z=1: k -> [B,H,S,HD]; z=2: v -> v^T [B,H,HD,S]
__global__ __launch_bounds__(256) void proj3_kernel(
    const unsigned short* __restrict__ A0, const unsigned short* __restrict__ A1,
    const unsigned short* __restrict__ A2,
    const unsigned short* __restrict__ W0, const unsigned short* __restrict__ W1,
    const unsigned short* __restrict__ W2,
    const float* __restrict__ b0, const float* __restrict__ b1, const float* __restrict__ b2,
    unsigned short* __restrict__ oq, unsigned short* __restrict__ ok,
    unsigned short* __restrict__ ovt) {
  const int z = blockIdx.z;
  const unsigned short* A  = (z == 0) ? A0 : (z == 1) ? A1 : A2;
  const unsigned short* Wt = (z == 0) ? W0 : (z == 1) ? W1 : W2;
  const float* bias        = (z == 0) ? b0 : (z == 1) ? b1 : b2;

  __shared__ __align__(16) unsigned short As[128 * 32];
  __shared__ __align__(16) unsigned short Bs[128 * 32];

  const int tid = threadIdx.x;
  const int lane = tid & 63, w = tid >> 6, ln = lane & 15, quad = lane >> 4;
  const int wm = (w & 1) * 64, wn = (w >> 1) * 64;
  const int n0 = blockIdx.x * 128, m0 = blockIdx.y * 128;

  const int slr = lane >> 2;
  const int schunk = (lane & 3) ^ ((lane >> 3) & 3);
  const int cfrag = (quad ^ ((ln >> 1) & 3)) * 8;

  f4v zero = {0.f, 0.f, 0.f, 0.f};
  f4v acc[4][4];
  for (int mi = 0; mi < 4; ++mi)
    for (int ni = 0; ni < 4; ++ni) acc[mi][ni] = zero;

  for (int kt = 0; kt < 1024; kt += 32) {
    __syncthreads();
    gll16(&A[(size_t)(m0 + w * 32 + slr) * 1024 + kt + schunk * 8],        &As[(w * 32) * 32]);
    gll16(&A[(size_t)(m0 + w * 32 + 16 + slr) * 1024 + kt + schunk * 8],   &As[(w * 32 + 16) * 32]);
    gll16(&Wt[(size_t)(n0 + w * 32 + slr) * 1024 + kt + schunk * 8],       &Bs[(w * 32) * 32]);
    gll16(&Wt[(size_t)(n0 + w * 32 + 16 + slr) * 1024 + kt + schunk * 8],  &Bs[(w * 32 + 16) * 32]);
    __syncthreads();
    s8v a[4], b[4];
    for (int mi = 0; mi < 4; ++mi) a[mi] = *(const s8v*)&As[(wm + mi * 16 + ln) * 32 + cfrag];
    for (int ni = 0; ni < 4; ++ni) b[ni] = *(const s8v*)&Bs[(wn + ni * 16 + ln) * 32 + cfrag];
    if (z < 2) {
      for (int mi = 0; mi < 4; ++mi)
        for (int ni = 0; ni < 4; ++ni)
          acc[mi][ni] = __builtin_amdgcn_mfma_f32_16x16x32_bf16(a[mi], b[ni], acc[mi][ni], 0, 0, 0);
    } else {
      for (int mi = 0; mi < 4; ++mi)
        for (int ni = 0; ni < 4; ++ni)
          acc[mi][ni] = __builtin_amdgcn_mfma_f32_16x16x32_bf16(b[ni], a[mi], acc[mi][ni], 0, 0, 0);
    }
  }

  if (z < 2) {
    const float qscale = (z == 0) ? 0.18033688f : 1.0f;  // 0.125 * log2(e)
    unsigned short* outp = (z == 0) ? oq : ok;
    for (int mi = 0; mi < 4; ++mi) {
      int rb = m0 + wm + mi * 16 + quad * 4;
      int b_ = rb >> 11;
      for (int ni = 0; ni < 4; ++ni) {
        int col = n0 + wn + ni * 16 + ln;
        float bvv = bias[col];
        int h = col >> 6, hd = col & 63;
        size_t ob = (size_t)(b_ * 16 + h) * 2048;
        for (int r = 0; r < 4; ++r) {
          int s = (rb + r) & 2047;
          outp[(ob + s) * 64 + hd] = f2bf((acc[mi][ni][r] + bvv) * qscale);
        }
      }
    }
  } else {
    // swapped: C row = weight col, C col = s
    for (int ni = 0; ni < 4; ++ni) {
      for (int r = 0; r < 4; ++r) {
        int colw = n0 + wn + ni * 16 + quad * 4 + r;
        int h = colw >> 6, hd = colw & 63;
        float bvv = bias[colw];
        for (int mi = 0; mi < 4; ++mi) {
          int sg = m0 + wm + mi * 16 + ln;
          int b_ = sg >> 11, ss = sg & 2047;
          ovt[((size_t)(b_ * 16 + h) * 64 + hd) * 2048 + ss] = f2bf(acc[mi][ni][r] + bvv);
        }
      }
    }
  }
}

// ---------- flash attention (R6): S^T orientation, 128-row Q tile, MFMA lsum ----------
__global__ __launch_bounds__(256) void flash_kernel(
    const unsigned short* __restrict__ q, const unsigned short* __restrict__ k,
    const unsigned short* __restrict__ vt, const u64* __restrict__ bm,
    unsigned short* __restrict__ ctx) {
  __shared__ __align__(16) unsigned short qp_s[128][72];  // q tile, then P[qrow][key]
  __shared__ __align__(16) unsigned short k_s[64][72];
  __shared__ __align__(16) unsigned short v_s[80][72];    // rows 64..79: ones row + zeros

  const int tid = threadIdx.x;
  const int lane = tid & 63, w = tid >> 6, ln = lane & 15, quad = lane >> 4;
  const int q0 = blockIdx.x * 128;
  const int bh = blockIdx.y;
  const unsigned short* qg  = q  + ((size_t)bh * 2048 + q0) * 64;
  const unsigned short* kgb = k  + (size_t)bh * 2048 * 64;
  const unsigned short* vgb = vt + (size_t)bh * 64 * 2048;

  for (int j = 0; j < 5; ++j) {
    int idx = j * 256 + tid;
    if (idx < 16 * 72) ((unsigned short*)v_s[64])[idx] = 0;
  }
  for (int p = 0; p < 4; ++p) {
    int c = p * 256 + tid;
    int row = c >> 3, c8 = c & 7;
    *(uint4*)&qp_s[row][c8 * 8] = *(const uint4*)&qg[(size_t)row * 64 + c8 * 8];
  }
  __syncthreads();
  if (tid < 64) v_s[64][tid] = 0x3F80;  // 1.0bf16
  __syncthreads();

  s8v aq[2][2];
  for (int s = 0; s < 2; ++s)
    for (int h = 0; h < 2; ++h)
      aq[s][h] = *(const s8v*)&qp_s[s * 64 + w * 16 + ln][h * 32 + quad * 8];
  s8v bones0 = *(const s8v*)&v_s[64 + ln][quad * 8];
  s8v bones1 = *(const s8v*)&v_s[64 + ln][32 + quad * 8];

  const int srow0 = tid >> 3, sc8 = tid & 7;
  const int srow1 = 32 + srow0;

  const u64* bmr0 = bm + (size_t)(q0 + w * 16 + ln) * 32;
  const u64* bmr1 = bmr0 + 64 * 32;

  uint4 kr0 = *(const uint4*)&kgb[(size_t)srow0 * 64 + sc8 * 8];
  uint4 kr1 = *(const uint4*)&kgb[(size_t)srow1 * 64 + sc8 * 8];
  uint4 vr0 = *(const uint4*)&vgb[(size_t)srow0 * 2048 + sc8 * 8];
  uint4 vr1 = *(const uint4*)&vgb[(size_t)srow1 * 2048 + sc8 * 8];
  u64 mwc[2], mwn[2];
  mwc[0] = bmr0[0];
  mwc[1] = bmr1[0];

  f4v zero = {0.f, 0.f, 0.f, 0.f};
  f4v l_acc[2];
  f4v o_acc[2][4];
  for (int s = 0; s < 2; ++s) {
    l_acc[s] = zero;
    for (int ni = 0; ni < 4; ++ni) o_acc[s][ni] = zero;
  }

  for (int kt = 0; kt < 2048; kt += 64) {
    *(uint4*)&k_s[srow0][sc8 * 8] = kr0;
    *(uint4*)&k_s[srow1][sc8 * 8] = kr1;
    *(uint4*)&v_s[srow0][sc8 * 8] = vr0;
    *(uint4*)&v_s[srow1][sc8 * 8] = vr1;
    if (kt + 64 < 2048) {
      int ktn = kt + 64;
      kr0 = *(const uint4*)&kgb[(size_t)(ktn + srow0) * 64 + sc8 * 8];
      kr1 = *(const uint4*)&kgb[(size_t)(ktn + srow1) * 64 + sc8 * 8];
      vr0 = *(const uint4*)&vgb[(size_t)srow0 * 2048 + ktn + sc8 * 8];
      vr1 = *(const uint4*)&vgb[(size_t)srow1 * 2048 + ktn + sc8 * 8];
      int ktcn = ktn >> 6;
      mwn[0] = bmr0[ktcn];
      mwn[1] = bmr1[ktcn];
    }
    __syncthreads();

    f4v sc[2][4];
    for (int ni = 0; ni < 4; ++ni) {
      s8v ak0 = *(const s8v*)&k_s[ni * 16 + ln][quad * 8];
      s8v ak1 = *(const s8v*)&k_s[ni * 16 + ln][32 + quad * 8];
      for (int s = 0; s < 2; ++s) {
        f4v t = zero;
        t = __builtin_amdgcn_mfma_f32_16x16x32_bf16(ak0, aq[s][0], t, 0, 0, 0);
        t = __builtin_amdgcn_mfma_f32_16x16x32_bf16(ak1, aq[s][1], t, 0, 0, 0);
        sc[s][ni] = t;
      }
    }

    for (int s = 0; s < 2; ++s) {
      u64 m = mwc[s] >> (quad * 4);
      unsigned mlo = (unsigned)m, mhi = (unsigned)(m >> 32);
      for (int ni = 0; ni < 4; ++ni) {
        unsigned msel = ((ni < 2) ? mlo : mhi) >> ((ni & 1) * 16);
        unsigned u0 = __float_as_uint(__builtin_amdgcn_exp2f(sc[s][ni][0]) * (float)(msel & 1u));
        unsigned u1 = __float_as_uint(__builtin_amdgcn_exp2f(sc[s][ni][1]) * (float)((msel >> 1) & 1u));
        unsigned u2 = __float_as_uint(__builtin_amdgcn_exp2f(sc[s][ni][2]) * (float)((msel >> 2) & 1u));
        unsigned u3 = __float_as_uint(__builtin_amdgcn_exp2f(sc[s][ni][3]) * (float)((msel >> 3) & 1u));
        unsigned plo = __builtin_amdgcn_perm(u1, u0, 0x07060302);
        unsigned phi = __builtin_amdgcn_perm(u3, u2, 0x07060302);
        *(u64*)&qp_s[s * 64 + w * 16 + ln][ni * 16 + quad * 4] = plo | ((u64)phi << 32);
      }
      mwc[s] = mwn[s];
    }

    s8v ap[2][2];
    for (int s = 0; s < 2; ++s)
      for (int h = 0; h < 2; ++h)
        ap[s][h] = *(const s8v*)&qp_s[s * 64 + w * 16 + ln][h * 32 + quad * 8];
    for (int ni = 0; ni < 4; ++ni) {
      s8v bv0 = *(const s8v*)&v_s[ni * 16 + ln][quad * 8];
      s8v bv1 = *(const s8v*)&v_s[ni * 16 + ln][32 + quad * 8];
      for (int s = 0; s < 2; ++s) {
        o_acc[s][ni] = __builtin_amdgcn_mfma_f32_16x16x32_bf16(ap[s][0], bv0, o_acc[s][ni], 0, 0, 0);
        o_acc[s][ni] = __builtin_amdgcn_mfma_f32_16x16x32_bf16(ap[s][1], bv1, o_acc[s][ni], 0, 0, 0);
      }
    }
    for (int s = 0; s < 2; ++s) {
      l_acc[s] = __builtin_amdgcn_mfma_f32_16x16x32_bf16(ap[s][0], bones0, l_acc[s], 0, 0, 0);
      l_acc[s] = __builtin_amdgcn_mfma_f32_16x16x32_bf16(ap[s][1], bones1, l_acc[s], 0, 0, 0);
    }
    __syncthreads();
  }

  int b_ = bh >> 4, h = bh & 15;
  for (int s = 0; s < 2; ++s) {
    for (int r = 0; r < 4; ++r) {
      float lr = __shfl(l_acc[s][r], quad * 16);
      float inv = 1.f / lr;
      int srow = q0 + s * 64 + w * 16 + quad * 4 + r;
      size_t base = ((size_t)b_ * 2048 + srow) * 1024 + h * 64;
      for (int ni = 0; ni < 4; ++ni)
        ctx[base + ni * 16 + ln] = f2bf(o_acc[s][ni][r] * inv);
    }
  }
}

// ---------- output projection, 64x128 tile, n-major grid ----------
__global__ __launch_bounds__(256) void gemm_out_kernel(
    const unsigned short* __restrict__ A, const unsigned short* __restrict__ Wt,
    const float* __restrict__ bias, float* __restrict__ out) {
  __shared__ __align__(16) unsigned short As[64 * 32];
  __shared__ __align__(16) unsigned short Bs[128 * 32];

  const int tid = threadIdx.x;
  const int lane = tid & 63, w = tid >> 6, ln = lane & 15, quad = lane >> 4;
  const int wm = (w & 1) * 32, wn = (w >> 1) * 64;
  const int n0 = blockIdx.x * 128, m0 = blockIdx.y * 64;

  const int slr = lane >> 2;
  const int schunk = (lane & 3) ^ ((lane >> 3) & 3);
  const int cfrag = (quad ^ ((ln >> 1) & 3)) * 8;

  f4v zero = {0.f, 0.f, 0.f, 0.f};
  f4v acc[2][4];
  for (int mi = 0; mi < 2; ++mi)
    for (int ni = 0; ni < 4; ++ni) acc[mi][ni] = zero;

  for (int kt = 0; kt < 1024; kt += 32) {
    __syncthreads();
    gll16(&A[(size_t)(m0 + w * 16 + slr) * 1024 + kt + schunk * 8],        &As[(w * 16) * 32]);
    gll16(&Wt[(size_t)(n0 + w * 32 + slr) * 1024 + kt + schunk * 8],       &Bs[(w * 32) * 32]);
    gll16(&Wt[(size_t)(n0 + w * 32 + 16 + slr) * 1024 + kt + schunk * 8],  &Bs[(w * 32 + 16) * 32]);
    __syncthreads();
    s8v a[2], b[4];
    for (int mi = 0; mi < 2; ++mi) a[mi] = *(const s8v*)&As[(wm + mi * 16 + ln) * 32 + cfrag];
    for (int ni = 0; ni < 4; ++ni) b[ni] = *(const s8v*)&Bs[(wn + ni * 16 + ln) * 32 + cfrag];
    for (int mi = 0; mi < 2; ++mi)
      for (int ni = 0; ni < 4; ++ni)
        acc[mi][ni] = __builtin_amdgcn_mfma_f32_16x16x32_bf16(a[mi], b[ni], acc[mi][ni], 0, 0, 0);
  }

  for (int mi = 0; mi < 2; ++mi) {
    int rb = m0 + wm + mi * 16 + quad * 4;
    for (int ni = 0; ni < 4; ++ni) {
      int col = n0 + wn + ni * 16 + ln;
      float bvv = bias[col];
      for (int r = 0; r < 4; ++r)
        out[(size_t)(rb + r) * 1024 + col] = acc[mi][ni][r] + bvv;
    }
  }
}

extern "C" void kernel_launch(void* const* d_in, const int* in_sizes, int n_in,
                              void* d_out, int out_size, void* d_ws, size_t ws_size,
                              hipStream_t stream) {
  const float* Q  = (const float*)d_in[0];
  const float* K  = (const float*)d_in[1];
  const float* V  = (const float*)d_in[2];
  const int* mask = (const int*)d_in[3];
  const float* Wq = (const float*)d_in[4];
  const float* bq = (const float*)d_in[5];
  const float* Wk = (const float*)d_in[6];
  const float* bk = (const float*)d_in[7];
  const float* Wv = (const float*)d_in[8];
  const float* bv = (const float*)d_in[9];
  const float* Wo = (const float*)d_in[10];
  const float* bo = (const float*)d_in[11];
  float* out = (float*)d_out;

  char* ws = (char*)d_ws;
  const size_t MB = 1u << 20;
  unsigned short* qb  = (unsigned short*)(ws + 0 * MB);
  unsigned short* kb  = (unsigned short*)(ws + 8 * MB);
  unsigned short* vb  = (unsigned short*)(ws + 16 * MB);
  unsigned short* wqt = (unsigned short*)(ws + 24 * MB);
  unsigned short* wkt = (unsigned short*)(ws + 26 * MB);
  unsigned short* wvt = (unsigned short*)(ws + 28 * MB);
  unsigned short* wot = (unsigned short*)(ws + 30 * MB);
  unsigned short* qh  = (unsigned short*)(ws + 32 * MB);
  unsigned short* kh  = (unsigned short*)(ws + 40 * MB);
  unsigned short* vth = (unsigned short*)(ws + 48 * MB);
  u64* bm             = (u64*)(ws + 56 * MB);
  unsigned short* ctx = (unsigned short*)(ws + 16 * MB);  // aliases vb (dead after proj3)

  prep_kernel<<<29696, 256, 0, stream>>>(Q, K, V, qb, kb, vb,
                                         Wq, Wk, Wv, Wo, wqt, wkt, wvt, wot,
                                         mask, bm);
  proj3_kernel<<<dim3(8, 32, 3), 256, 0, stream>>>(qb, kb, vb, wqt, wkt, wvt,
                                                   bq, bk, bv, qh, kh, vth);
  flash_kernel<<<dim3(16, 32), 256, 0, stream>>>(qh, kh, vth, bm, ctx);
  gemm_out_kernel<<<dim3(8, 64), 256, 0, stream>>>(ctx, wot, bo, out);
}

// Round 9
// 258.654 us; speedup vs baseline: 1.1182x; 1.0229x over previous
//
#include <hip/hip_runtime.h>

// MHA: B=2, S=2048, D=1024, H=16, HD=64. fp32 in/out, bf16 MFMA internally.
// ws layout (64 MB): qb/kb/vb bf16 [4096,1024] @0/8/16MB; Wq/k/v/o^T bf16
// [1024,1024] @24/26/28/30MB; q(pre-scaled 0.125*log2e),k [B,H,S,HD] @32/40MB;
// v^T [B,H,HD,S] @48MB; bm u64[2048][32] @56MB; ctx bf16 @16MB (aliases vb).
//
// R9: flash -> 512-thread blocks (8 waves, each owns 16 q-rows of the 128-row
// tile). Grid stays 512 blocks; waves/CU 8->16 (occupancy ceiling 25->50%).
// Per-wave instruction stream halves; no extra traffic, no atomics (the R7
// split-K lesson). proj3/gemm_out = R6 config (64x128 tiles, best total).

using s8v = __attribute__((ext_vector_type(8))) short;   // 8 bf16 (4 VGPRs)
using f4v = __attribute__((ext_vector_type(4))) float;   // MFMA acc
typedef unsigned long long u64;

__device__ __forceinline__ unsigned short f2bf(float f) {
  union { float f; unsigned int u; } v; v.f = f;
  return (unsigned short)((v.u + 0x7fffu + ((v.u >> 16) & 1u)) >> 16);  // RNE
}

__device__ __forceinline__ void gll16(const void* g, void* l) {
  __builtin_amdgcn_global_load_lds(
      (const __attribute__((address_space(1))) unsigned int*)g,
      (__attribute__((address_space(3))) unsigned int*)l, 16, 0, 0);
}

// ---------- merged prep: f2b (QKV), wtrans (4 weights), packmask ----------
__global__ void prep_kernel(const float* __restrict__ Q, const float* __restrict__ K,
                            const float* __restrict__ V,
                            unsigned short* __restrict__ qb, unsigned short* __restrict__ kb,
                            unsigned short* __restrict__ vb,
                            const float* __restrict__ W0, const float* __restrict__ W1,
                            const float* __restrict__ W2, const float* __restrict__ W3,
                            unsigned short* __restrict__ T0, unsigned short* __restrict__ T1,
                            unsigned short* __restrict__ T2, unsigned short* __restrict__ T3,
                            const int* __restrict__ mask, u64* __restrict__ bm) {
  __shared__ unsigned short t[64][72];
  const int bid = blockIdx.x, tid = threadIdx.x;
  if (bid < 12288) {
    int z = bid >> 12;
    int idx = (bid & 4095) * 256 + tid;
    const float* in = (z == 0) ? Q : (z == 1) ? K : V;
    unsigned short* out = (z == 0) ? qb : (z == 1) ? kb : vb;
    float4 v = ((const float4*)in)[idx];
    ushort4 o;
    o.x = f2bf(v.x); o.y = f2bf(v.y); o.z = f2bf(v.z); o.w = f2bf(v.w);
    ((ushort4*)out)[idx] = o;
  } else if (bid < 13312) {
    int b = bid - 12288;
    int z = b >> 8, rem = b & 255;
    int k0 = (rem >> 4) * 64, n0 = (rem & 15) * 64;
    const float* W = (z == 0) ? W0 : (z == 1) ? W1 : (z == 2) ? W2 : W3;
    unsigned short* Wt = (z == 0) ? T0 : (z == 1) ? T1 : (z == 2) ? T2 : T3;
    for (int p = 0; p < 4; ++p) {
      int idx = p * 256 + tid;
      int row = idx >> 4, c4 = idx & 15;
      float4 v = *(const float4*)&W[(size_t)(k0 + row) * 1024 + n0 + c4 * 4];
      t[row][c4 * 4 + 0] = f2bf(v.x);
      t[row][c4 * 4 + 1] = f2bf(v.y);
      t[row][c4 * 4 + 2] = f2bf(v.z);
      t[row][c4 * 4 + 3] = f2bf(v.w);
    }
    __syncthreads();
    for (int p = 0; p < 2; ++p) {
      int idx = p * 256 + tid;
      int j = idx >> 3, c8 = idx & 7;
      unsigned short tmp[8];
      for (int i = 0; i < 8; ++i) tmp[i] = t[c8 * 8 + i][j];
      uint4 o;
      o.x = tmp[0] | ((unsigned)tmp[1] << 16);
      o.y = tmp[2] | ((unsigned)tmp[3] << 16);
      o.z = tmp[4] | ((unsigned)tmp[5] << 16);
      o.w = tmp[6] | ((unsigned)tmp[7] << 16);
      *(uint4*)&Wt[(size_t)(n0 + j) * 1024 + k0 + c8 * 8] = o;
    }
  } else {
    int b = bid - 13312;
    int gw = (b * 256 + tid) >> 6;
    int lane = tid & 63;
    int mv = mask[(size_t)gw * 64 + lane];
    u64 bal = __ballot(mv != 0);
    if (lane == 0) bm[gw] = bal;
  }
}

// ---------- fused QKV projection GEMM, 64x128 tile (R6 config) ----------
// z=0: q*(0.125*log2e) -> [B,H,S,HD]; z=1: k -> [B,H,S,HD]; z=2: v -> v^T [B,H,HD,S]
__global__ __launch_bounds__(256) void proj3_kernel(
    const unsigned short* __restrict__ A0, const unsigned short* __restrict__ A1,
    const unsigned short* __restrict__ A2,
    const unsigned short* __restrict__ W0, const unsigned short* __restrict__ W1,
    const unsigned short* __restrict__ W2,
    const float* __restrict__ b0, const float* __restrict__ b1, const float* __restrict__ b2,
    unsigned short* __restrict__ oq, unsigned short* __restrict__ ok,
    unsigned short* __restrict__ ovt) {
  const int z = blockIdx.z;
  const unsigned short* A  = (z == 0) ? A0 : (z == 1) ? A1 : A2;
  const unsigned short* Wt = (z == 0) ? W0 : (z == 1) ? W1 : W2;
  const float* bias        = (z == 0) ? b0 : (z == 1) ? b1 : b2;

  __shared__ __align__(16) unsigned short As[64 * 32];
  __shared__ __align__(16) unsigned short Bs[128 * 32];

  const int tid = threadIdx.x;
  const int lane = tid & 63, w = tid >> 6, ln = lane & 15, quad = lane >> 4;
  const int wm = (w & 1) * 32, wn = (w >> 1) * 64;
  const int m0 = blockIdx.x * 64, n0 = blockIdx.y * 128;

  const int slr = lane >> 2;
  const int schunk = (lane & 3) ^ ((lane >> 3) & 3);
  const int cfrag = (quad ^ ((ln >> 1) & 3)) * 8;

  f4v zero = {0.f, 0.f, 0.f, 0.f};
  f4v acc[2][4];
  for (int mi = 0; mi < 2; ++mi)
    for (int ni = 0; ni < 4; ++ni) acc[mi][ni] = zero;

  for (int kt = 0; kt < 1024; kt += 32) {
    __syncthreads();
    gll16(&A[(size_t)(m0 + w * 16 + slr) * 1024 + kt + schunk * 8],        &As[(w * 16) * 32]);
    gll16(&Wt[(size_t)(n0 + w * 32 + slr) * 1024 + kt + schunk * 8],       &Bs[(w * 32) * 32]);
    gll16(&Wt[(size_t)(n0 + w * 32 + 16 + slr) * 1024 + kt + schunk * 8],  &Bs[(w * 32 + 16) * 32]);
    __syncthreads();
    s8v a[2], b[4];
    for (int mi = 0; mi < 2; ++mi) a[mi] = *(const s8v*)&As[(wm + mi * 16 + ln) * 32 + cfrag];
    for (int ni = 0; ni < 4; ++ni) b[ni] = *(const s8v*)&Bs[(wn + ni * 16 + ln) * 32 + cfrag];
    if (z < 2) {
      for (int mi = 0; mi < 2; ++mi)
        for (int ni = 0; ni < 4; ++ni)
          acc[mi][ni] = __builtin_amdgcn_mfma_f32_16x16x32_bf16(a[mi], b[ni], acc[mi][ni], 0, 0, 0);
    } else {
      for (int mi = 0; mi < 2; ++mi)
        for (int ni = 0; ni < 4; ++ni)
          acc[mi][ni] = __builtin_amdgcn_mfma_f32_16x16x32_bf16(b[ni], a[mi], acc[mi][ni], 0, 0, 0);
    }
  }

  if (z < 2) {
    const float qscale = (z == 0) ? 0.18033688f : 1.0f;  // 0.125 * log2(e)
    unsigned short* outp = (z == 0) ? oq : ok;
    for (int mi = 0; mi < 2; ++mi) {
      int rb = m0 + wm + mi * 16 + quad * 4;
      int b_ = rb >> 11;
      for (int ni = 0; ni < 4; ++ni) {
        int col = n0 + wn + ni * 16 + ln;
        float bvv = bias[col];
        int h = col >> 6, hd = col & 63;
        size_t ob = (size_t)(b_ * 16 + h) * 2048;
        for (int r = 0; r < 4; ++r) {
          int s = (rb + r) & 2047;
          outp[(ob + s) * 64 + hd] = f2bf((acc[mi][ni][r] + bvv) * qscale);
        }
      }
    }
  } else {
    for (int ni = 0; ni < 4; ++ni) {
      for (int r = 0; r < 4; ++r) {
        int colw = n0 + wn + ni * 16 + quad * 4 + r;
        int h = colw >> 6, hd = colw & 63;
        float bvv = bias[colw];
        for (int mi = 0; mi < 2; ++mi) {
          int sg = m0 + wm + mi * 16 + ln;
          int b_ = sg >> 11, ss = sg & 2047;
          ovt[((size_t)(b_ * 16 + h) * 64 + hd) * 2048 + ss] = f2bf(acc[mi][ni][r] + bvv);
        }
      }
    }
  }
}

// ---------- flash attention: 512 threads, 8 waves x 16 q-rows, MFMA lsum ----------
__global__ __launch_bounds__(512) void flash_kernel(
    const unsigned short* __restrict__ q, const unsigned short* __restrict__ k,
    const unsigned short* __restrict__ vt, const u64* __restrict__ bm,
    unsigned short* __restrict__ ctx) {
  __shared__ __align__(16) unsigned short qp_s[128][72];  // q tile, then P[qrow][key]
  __shared__ __align__(16) unsigned short k_s[64][72];
  __shared__ __align__(16) unsigned short v_s[80][72];    // rows 64..79: ones row + zeros

  const int tid = threadIdx.x;
  const int lane = tid & 63, w = tid >> 6, ln = lane & 15, quad = lane >> 4;
  const int q0 = blockIdx.x * 128;
  const int bh = blockIdx.y;
  const unsigned short* qg  = q  + ((size_t)bh * 2048 + q0) * 64;
  const unsigned short* kgb = k  + (size_t)bh * 2048 * 64;
  const unsigned short* vgb = vt + (size_t)bh * 64 * 2048;

  // init v_s rows 64..79 (zeros; row 64 becomes ones); stage q tile 128x64
  for (int j = 0; j < 3; ++j) {
    int idx = j * 512 + tid;
    if (idx < 16 * 72) ((unsigned short*)v_s[64])[idx] = 0;
  }
  for (int p = 0; p < 2; ++p) {
    int c = p * 512 + tid;
    int row = c >> 3, c8 = c & 7;
    *(uint4*)&qp_s[row][c8 * 8] = *(const uint4*)&qg[(size_t)row * 64 + c8 * 8];
  }
  __syncthreads();
  if (tid < 64) v_s[64][tid] = 0x3F80;  // 1.0bf16
  __syncthreads();

  // q fragments: wave w owns q-rows [w*16, w*16+16)
  s8v aq0 = *(const s8v*)&qp_s[w * 16 + ln][quad * 8];
  s8v aq1 = *(const s8v*)&qp_s[w * 16 + ln][32 + quad * 8];
  s8v bones0 = *(const s8v*)&v_s[64 + ln][quad * 8];
  s8v bones1 = *(const s8v*)&v_s[64 + ln][32 + quad * 8];

  // k/v staging: 512 threads x 1 uint4 per array
  const int srow = tid >> 3, sc8 = tid & 7;

  const u64* bmr = bm + (size_t)(q0 + w * 16 + ln) * 32;

  uint4 kr = *(const uint4*)&kgb[(size_t)srow * 64 + sc8 * 8];
  uint4 vr = *(const uint4*)&vgb[(size_t)srow * 2048 + sc8 * 8];
  u64 mwc = bmr[0], mwn;

  f4v zero = {0.f, 0.f, 0.f, 0.f};
  f4v l_acc = zero;
  f4v o_acc[4];
  for (int ni = 0; ni < 4; ++ni) o_acc[ni] = zero;

  for (int kt = 0; kt < 2048; kt += 64) {
    *(uint4*)&k_s[srow][sc8 * 8] = kr;
    *(uint4*)&v_s[srow][sc8 * 8] = vr;
    if (kt + 64 < 2048) {
      int ktn = kt + 64;
      kr = *(const uint4*)&kgb[(size_t)(ktn + srow) * 64 + sc8 * 8];
      vr = *(const uint4*)&vgb[(size_t)srow * 2048 + ktn + sc8 * 8];
      mwn = bmr[ktn >> 6];
    }
    __syncthreads();

    // S^T = K·Q^T: A = K-frag (m=key), B = Q-frag (n=qrow)
    f4v sc[4];
    for (int ni = 0; ni < 4; ++ni) {
      s8v ak0 = *(const s8v*)&k_s[ni * 16 + ln][quad * 8];
      s8v ak1 = *(const s8v*)&k_s[ni * 16 + ln][32 + quad * 8];
      f4v t = zero;
      t = __builtin_amdgcn_mfma_f32_16x16x32_bf16(ak0, aq0, t, 0, 0, 0);
      t = __builtin_amdgcn_mfma_f32_16x16x32_bf16(ak1, aq1, t, 0, 0, 0);
      sc[ni] = t;
    }

    // p = 2^score * maskbit; pack pairs via v_perm; write b64 to P (wave-private rows)
    {
      u64 m = mwc >> (quad * 4);
      unsigned mlo = (unsigned)m, mhi = (unsigned)(m >> 32);
      for (int ni = 0; ni < 4; ++ni) {
        unsigned msel = ((ni < 2) ? mlo : mhi) >> ((ni & 1) * 16);
        unsigned u0 = __float_as_uint(__builtin_amdgcn_exp2f(sc[ni][0]) * (float)(msel & 1u));
        unsigned u1 = __float_as_uint(__builtin_amdgcn_exp2f(sc[ni][1]) * (float)((msel >> 1) & 1u));
        unsigned u2 = __float_as_uint(__builtin_amdgcn_exp2f(sc[ni][2]) * (float)((msel >> 2) & 1u));
        unsigned u3 = __float_as_uint(__builtin_amdgcn_exp2f(sc[ni][3]) * (float)((msel >> 3) & 1u));
        unsigned plo = __builtin_amdgcn_perm(u1, u0, 0x07060302);
        unsigned phi = __builtin_amdgcn_perm(u3, u2, 0x07060302);
        *(u64*)&qp_s[w * 16 + ln][ni * 16 + quad * 4] = plo | ((u64)phi << 32);
      }
      mwc = mwn;
    }

    // P @ V, plus l = P @ ones
    s8v ap0 = *(const s8v*)&qp_s[w * 16 + ln][quad * 8];
    s8v ap1 = *(const s8v*)&qp_s[w * 16 + ln][32 + quad * 8];
    for (int ni = 0; ni < 4; ++ni) {
      s8v bv0 = *(const s8v*)&v_s[ni * 16 + ln][quad * 8];
      s8v bv1 = *(const s8v*)&v_s[ni * 16 + ln][32 + quad * 8];
      o_acc[ni] = __builtin_amdgcn_mfma_f32_16x16x32_bf16(ap0, bv0, o_acc[ni], 0, 0, 0);
      o_acc[ni] = __builtin_amdgcn_mfma_f32_16x16x32_bf16(ap1, bv1, o_acc[ni], 0, 0, 0);
    }
    l_acc = __builtin_amdgcn_mfma_f32_16x16x32_bf16(ap0, bones0, l_acc, 0, 0, 0);
    l_acc = __builtin_amdgcn_mfma_f32_16x16x32_bf16(ap1, bones1, l_acc, 0, 0, 0);
    __syncthreads();
  }

  // l for qrow quad*4+r sits in lane quad*16 (ln=0), reg r
  int b_ = bh >> 4, h = bh & 15;
  for (int r = 0; r < 4; ++r) {
    float lr = __shfl(l_acc[r], quad * 16);
    float inv = 1.f / lr;
    int srow_ = q0 + w * 16 + quad * 4 + r;
    size_t base = ((size_t)b_ * 2048 + srow_) * 1024 + h * 64;
    for (int ni = 0; ni < 4; ++ni)
      ctx[base + ni * 16 + ln] = f2bf(o_acc[ni][r] * inv);
  }
}

// ---------- output projection, 64x128 tile (R6 config) ----------
__global__ __launch_bounds__(256) void gemm_out_kernel(
    const unsigned short* __restrict__ A, const unsigned short* __restrict__ Wt,
    const float* __restrict__ bias, float* __restrict__ out) {
  __shared__ __align__(16) unsigned short As[64 * 32];
  __shared__ __align__(16) unsigned short Bs[128 * 32];

  const int tid = threadIdx.x;
  const int lane = tid & 63, w = tid >> 6, ln = lane & 15, quad = lane >> 4;
  const int wm = (w & 1) * 32, wn = (w >> 1) * 64;
  const int m0 = blockIdx.x * 64, n0 = blockIdx.y * 128;

  const int slr = lane >> 2;
  const int schunk = (lane & 3) ^ ((lane >> 3) & 3);
  const int cfrag = (quad ^ ((ln >> 1) & 3)) * 8;

  f4v zero = {0.f, 0.f, 0.f, 0.f};
  f4v acc[2][4];
  for (int mi = 0; mi < 2; ++mi)
    for (int ni = 0; ni < 4; ++ni) acc[mi][ni] = zero;

  for (int kt = 0; kt < 1024; kt += 32) {
    __syncthreads();
    gll16(&A[(size_t)(m0 + w * 16 + slr) * 1024 + kt + schunk * 8],        &As[(w * 16) * 32]);
    gll16(&Wt[(size_t)(n0 + w * 32 + slr) * 1024 + kt + schunk * 8],       &Bs[(w * 32) * 32]);
    gll16(&Wt[(size_t)(n0 + w * 32 + 16 + slr) * 1024 + kt + schunk * 8],  &Bs[(w * 32 + 16) * 32]);
    __syncthreads();
    s8v a[2], b[4];
    for (int mi = 0; mi < 2; ++mi) a[mi] = *(const s8v*)&As[(wm + mi * 16 + ln) * 32 + cfrag];
    for (int ni = 0; ni < 4; ++ni) b[ni] = *(const s8v*)&Bs[(wn + ni * 16 + ln) * 32 + cfrag];
    for (int mi = 0; mi < 2; ++mi)
      for (int ni = 0; ni < 4; ++ni)
        acc[mi][ni] = __builtin_amdgcn_mfma_f32_16x16x32_bf16(a[mi], b[ni], acc[mi][ni], 0, 0, 0);
  }

  for (int mi = 0; mi < 2; ++mi) {
    int rb = m0 + wm + mi * 16 + quad * 4;
    for (int ni = 0; ni < 4; ++ni) {
      int col = n0 + wn + ni * 16 + ln;
      float bvv = bias[col];
      for (int r = 0; r < 4; ++r)
        out[(size_t)(rb + r) * 1024 + col] = acc[mi][ni][r] + bvv;
    }
  }
}

extern "C" void kernel_launch(void* const* d_in, const int* in_sizes, int n_in,
                              void* d_out, int out_size, void* d_ws, size_t ws_size,
                              hipStream_t stream) {
  const float* Q  = (const float*)d_in[0];
  const float* K  = (const float*)d_in[1];
  const float* V  = (const float*)d_in[2];
  const int* mask = (const int*)d_in[3];
  const float* Wq = (const float*)d_in[4];
  const float* bq = (const float*)d_in[5];
  const float* Wk = (const float*)d_in[6];
  const float* bk = (const float*)d_in[7];
  const float* Wv = (const float*)d_in[8];
  const float* bv = (const float*)d_in[9];
  const float* Wo = (const float*)d_in[10];
  const float* bo = (const float*)d_in[11];
  float* out = (float*)d_out;

  char* ws = (char*)d_ws;
  const size_t MB = 1u << 20;
  unsigned short* qb  = (unsigned short*)(ws + 0 * MB);
  unsigned short* kb  = (unsigned short*)(ws + 8 * MB);
  unsigned short* vb  = (unsigned short*)(ws + 16 * MB);
  unsigned short* wqt = (unsigned short*)(ws + 24 * MB);
  unsigned short* wkt = (unsigned short*)(ws + 26 * MB);
  unsigned short* wvt = (unsigned short*)(ws + 28 * MB);
  unsigned short* wot = (unsigned short*)(ws + 30 * MB);
  unsigned short* qh  = (unsigned short*)(ws + 32 * MB);
  unsigned short* kh  = (unsigned short*)(ws + 40 * MB);
  unsigned short* vth = (unsigned short*)(ws + 48 * MB);
  u64* bm             = (u64*)(ws + 56 * MB);
  unsigned short* ctx = (unsigned short*)(ws + 16 * MB);  // aliases vb (dead after proj3)

  prep_kernel<<<29696, 256, 0, stream>>>(Q, K, V, qb, kb, vb,
                                         Wq, Wk, Wv, Wo, wqt, wkt, wvt, wot,
                                         mask, bm);
  proj3_kernel<<<dim3(64, 8, 3), 256, 0, stream>>>(qb, kb, vb, wqt, wkt, wvt,
                                                   bq, bk, bv, qh, kh, vth);
  flash_kernel<<<dim3(16, 32), 512, 0, stream>>>(qh, kh, vth, bm, ctx);
  gemm_out_kernel<<<dim3(64, 8), 256, 0, stream>>>(ctx, wot, bo, out);
}